// Round 3
// baseline (435.921 us; speedup 1.0000x reference)
//
#include <hip/hip_runtime.h>

typedef unsigned long long u64;
typedef unsigned short u16;
typedef __bf16 bf16_t;
typedef bf16_t bf16x8 __attribute__((ext_vector_type(8)));
typedef float f32x4 __attribute__((ext_vector_type(4)));

#define DEVI __device__ __forceinline__

DEVI float gelu_f(float x) { return 0.5f * x * (1.0f + erff(x * 0.70710678f)); }

DEVI u16 f2bf(float x) {  // round-to-nearest-even f32 -> bf16
  unsigned u = __float_as_uint(x);
  return (u16)((u + 0x7fffu + ((u >> 16) & 1u)) >> 16);
}

DEVI void ce64(u64& a, u64& b) { u64 lo = a < b ? a : b; u64 hi = a < b ? b : a; a = lo; b = hi; }

DEVI u64 shflx64(u64 v, int m) {
  unsigned lo = (unsigned)__shfl_xor((int)(v & 0xffffffffull), m, 64);
  unsigned hi = (unsigned)__shfl_xor((int)(v >> 32), m, 64);
  return ((u64)hi << 32) | lo;
}

// t, o both sorted ascending; t <- smallest 8 of union, sorted ascending.
DEVI void take8(u64 t[8], const u64 o[8]) {
  u64 s[8];
#pragma unroll
  for (int i = 0; i < 8; ++i) { u64 x = o[7 - i]; s[i] = (t[i] < x) ? t[i] : x; }
  ce64(s[0], s[4]); ce64(s[1], s[5]); ce64(s[2], s[6]); ce64(s[3], s[7]);
  ce64(s[0], s[2]); ce64(s[1], s[3]); ce64(s[4], s[6]); ce64(s[5], s[7]);
  ce64(s[0], s[1]); ce64(s[2], s[3]); ce64(s[4], s[5]); ce64(s[6], s[7]);
#pragma unroll
  for (int i = 0; i < 8; ++i) t[i] = s[i];
}

DEVI void insert8(u64 t[8], u64 c) {
  if (c < t[7]) {
    t[7] = c;
    ce64(t[6], t[7]); ce64(t[5], t[6]); ce64(t[4], t[5]); ce64(t[3], t[4]);
    ce64(t[2], t[3]); ce64(t[1], t[2]); ce64(t[0], t[1]);
  }
}

// ---------------- key norms + bf16 conversion ----------------
__global__ __launch_bounds__(256) void knormconv_kernel(const float* __restrict__ keys,
                                                        float* __restrict__ knorm,
                                                        u16* __restrict__ kbf) {
  int j = blockIdx.x * 256 + threadIdx.x;
  if (j >= 100000) return;
  const float4* kp = (const float4*)(keys + (size_t)j * 64);
  u16* op = kbf + (size_t)j * 64;
  float a0 = 0.f, a1 = 0.f;
#pragma unroll
  for (int u = 0; u < 16; u += 2) {
    float4 v0 = kp[u], v1 = kp[u + 1];
    a0 = fmaf(v0.x, v0.x, a0); a0 = fmaf(v0.y, v0.y, a0); a0 = fmaf(v0.z, v0.z, a0); a0 = fmaf(v0.w, v0.w, a0);
    a1 = fmaf(v1.x, v1.x, a1); a1 = fmaf(v1.y, v1.y, a1); a1 = fmaf(v1.z, v1.z, a1); a1 = fmaf(v1.w, v1.w, a1);
    ushort4 o0 = {f2bf(v0.x), f2bf(v0.y), f2bf(v0.z), f2bf(v0.w)};
    ushort4 o1 = {f2bf(v1.x), f2bf(v1.y), f2bf(v1.z), f2bf(v1.w)};
    *(ushort4*)(op + u * 4) = o0;
    *(ushort4*)(op + u * 4 + 4) = o1;
  }
  knorm[j] = a0 + a1;
}

// ---------------- q -> bf16 + qnorm ----------------
__global__ __launch_bounds__(256) void qprep_kernel(const float* __restrict__ qc,
                                                    u16* __restrict__ qbf,
                                                    float* __restrict__ qn) {
  int q = blockIdx.x * 256 + threadIdx.x;
  if (q >= 512) return;
  const float4* qp = (const float4*)(qc + (size_t)q * 64);
  u16* op = qbf + (size_t)q * 64;
  float s = 0.f;
#pragma unroll
  for (int u = 0; u < 16; ++u) {
    float4 v = qp[u];
    s = fmaf(v.x, v.x, fmaf(v.y, v.y, fmaf(v.z, v.z, fmaf(v.w, v.w, s))));
    ushort4 o = {f2bf(v.x), f2bf(v.y), f2bf(v.z), f2bf(v.w)};
    *(ushort4*)(op + u * 4) = o;
  }
  qn[q] = s;
}

// ---------------- W[K][N] fp32 -> Wt[N][K] bf16 ----------------
__global__ __launch_bounds__(256) void wconv_kernel(const float* __restrict__ W,
                                                    u16* __restrict__ Wt, int K, int N) {
  __shared__ float s[32][33];
  const int k0 = blockIdx.y * 32, n0 = blockIdx.x * 32;
  const int a = threadIdx.x >> 5, b = threadIdx.x & 31;
#pragma unroll
  for (int p = 0; p < 4; ++p) s[a + p * 8][b] = W[(size_t)(k0 + a + p * 8) * N + n0 + b];
  __syncthreads();
#pragma unroll
  for (int p = 0; p < 4; ++p) Wt[(size_t)(n0 + a + p * 8) * K + k0 + b] = f2bf(s[b][a + p * 8]);
}

// ---------------- tiled fp32 GEMM (encoder / h1c): C = act(A@W + bias) ----------------
template <int ACT, int BIAS>
__global__ __launch_bounds__(256) void gemm_kernel(const float* __restrict__ A,
                                                   const float* __restrict__ W,
                                                   const float* __restrict__ bias,
                                                   float* __restrict__ C,
                                                   int M, int N, int K) {
  __shared__ float As[16][68];
  __shared__ float Bs[16][68];
  const int tid = threadIdx.x;
  const int tx = tid & 15, ty = tid >> 4;
  const int ar = tid >> 2, ac = tid & 3;
  const int br = tid >> 4, bc = tid & 15;
  const int row0 = blockIdx.y * 64, col0 = blockIdx.x * 64;
  float acc[4][4] = {};
  for (int k0 = 0; k0 < K; k0 += 16) {
    float4 a4 = *(const float4*)(A + (size_t)(row0 + ar) * K + k0 + ac * 4);
    float4 b4 = *(const float4*)(W + (size_t)(k0 + br) * N + col0 + bc * 4);
    __syncthreads();
    As[ac * 4 + 0][ar] = a4.x;
    As[ac * 4 + 1][ar] = a4.y;
    As[ac * 4 + 2][ar] = a4.z;
    As[ac * 4 + 3][ar] = a4.w;
    *(float4*)(&Bs[br][bc * 4]) = b4;
    __syncthreads();
#pragma unroll
    for (int kk = 0; kk < 16; ++kk) {
      float4 av = *(const float4*)(&As[kk][ty * 4]);
      float4 bv = *(const float4*)(&Bs[kk][tx * 4]);
      float ar_[4] = {av.x, av.y, av.z, av.w};
      float br_[4] = {bv.x, bv.y, bv.z, bv.w};
#pragma unroll
      for (int i = 0; i < 4; ++i)
#pragma unroll
        for (int j = 0; j < 4; ++j) acc[i][j] = fmaf(ar_[i], br_[j], acc[i][j]);
    }
  }
  float bb[4] = {0.f, 0.f, 0.f, 0.f};
  if (BIAS) {
#pragma unroll
    for (int j = 0; j < 4; ++j) bb[j] = bias[col0 + tx * 4 + j];
  }
#pragma unroll
  for (int i = 0; i < 4; ++i) {
    float4 o;
    float v0 = acc[i][0] + bb[0];
    float v1 = acc[i][1] + bb[1];
    float v2 = acc[i][2] + bb[2];
    float v3 = acc[i][3] + bb[3];
    if (ACT) { v0 = gelu_f(v0); v1 = gelu_f(v1); v2 = gelu_f(v2); v3 = gelu_f(v3); }
    o.x = v0; o.y = v1; o.z = v2; o.w = v3;
    *(float4*)(C + (size_t)(row0 + ty * 4 + i) * N + col0 + tx * 4) = o;
  }
}

// ---------------- MFMA distance scan: per-(query,chunk) approx top-8 ----------------
// grid (64 chunks, 8 q-tiles), block 256 (4 waves, wave = 16 queries)
// D = K_tile(A) x Q(B): lane holds 4 keys for ONE query (col = lane&15)
__global__ __launch_bounds__(256) void dist_scan_kernel(const u16* __restrict__ qbf,
                                                        const float* __restrict__ qn,
                                                        const u16* __restrict__ kbf,
                                                        const float* __restrict__ knorm,
                                                        u64* __restrict__ cand) {
  const int NKEYS = 100000, CK = 1563, NCH = 64;
  const int tid = threadIdx.x;
  const int wave = tid >> 6, lane = tid & 63;
  const int g = lane >> 4, qi = lane & 15;
  const int qrow = blockIdx.y * 64 + wave * 16 + qi;
  const bf16x8 b0 = *(const bf16x8*)(qbf + (size_t)qrow * 64 + g * 8);
  const bf16x8 b1 = *(const bf16x8*)(qbf + (size_t)qrow * 64 + 32 + g * 8);
  const float qnv = qn[qrow];
  u64 t[8];
#pragma unroll
  for (int i = 0; i < 8; ++i) t[i] = ~0ull;
  const int c0 = blockIdx.x * CK;
  const int c1 = (c0 + CK < NKEYS) ? c0 + CK : NKEYS;
  for (int kt = c0; kt < c1; kt += 16) {
    const u16* kp = kbf + (size_t)(kt + qi) * 64 + g * 8;
    bf16x8 a0 = *(const bf16x8*)(kp);
    bf16x8 a1 = *(const bf16x8*)(kp + 32);
    f32x4 zz = {0.f, 0.f, 0.f, 0.f};
    f32x4 acc = __builtin_amdgcn_mfma_f32_16x16x32_bf16(a0, b0, zz, 0, 0, 0);
    acc = __builtin_amdgcn_mfma_f32_16x16x32_bf16(a1, b1, acc, 0, 0, 0);
    const float4 kn4 = *(const float4*)(knorm + kt + g * 4);
    const int kbase = kt + g * 4;
    float knr[4] = {kn4.x, kn4.y, kn4.z, kn4.w};
#pragma unroll
    for (int r = 0; r < 4; ++r) {
      const int kidx = kbase + r;
      float d2 = fmaf(-2.f, acc[r], qnv + knr[r]);
      d2 = fmaxf(d2, 0.f);
      u64 c = ((u64)__float_as_uint(d2) << 32) | (unsigned)kidx;
      if (kidx < c1) insert8(t, c);
    }
  }
  // merge the 4 lane-groups that share this query
  {
    u64 o[8];
#pragma unroll
    for (int i = 0; i < 8; ++i) o[i] = shflx64(t[i], 16);
    take8(t, o);
#pragma unroll
    for (int i = 0; i < 8; ++i) o[i] = shflx64(t[i], 32);
    take8(t, o);
  }
  if (lane < 16) {
    u64* cp = cand + ((size_t)qrow * NCH + blockIdx.x) * 8;
#pragma unroll
    for (int i = 0; i < 8; ++i) cp[i] = t[i];
  }
}

// ---------------- exact fp32 re-rank of 512 candidates -> final top-8 ----------------
// grid 512 (query), block 64 (1 wave); lane = chunk
__global__ __launch_bounds__(64) void rerank_kernel(const u64* __restrict__ cand,
                                                    const float* __restrict__ qc,
                                                    const float* __restrict__ qn,
                                                    const float* __restrict__ keys,
                                                    const float* __restrict__ knorm,
                                                    int* __restrict__ idxb,
                                                    float* __restrict__ wtsb,
                                                    float* __restrict__ conf) {
  const int q = blockIdx.x, lane = threadIdx.x;
  __shared__ float qs[64];
  if (lane < 16) *(float4*)(qs + lane * 4) = ((const float4*)(qc + (size_t)q * 64))[lane];
  __syncthreads();
  const float qnv = qn[q];
  u64 t[8];
#pragma unroll
  for (int i = 0; i < 8; ++i) t[i] = ~0ull;
  const u64* cp = cand + (size_t)q * 512 + (size_t)lane * 8;
#pragma unroll
  for (int i = 0; i < 8; ++i) {
    const int idx = (int)(unsigned)(cp[i] & 0xffffffffull);
    const float4* kr = (const float4*)(keys + (size_t)idx * 64);
    float a0 = 0.f, a1 = 0.f, a2 = 0.f, a3 = 0.f;
#pragma unroll
    for (int u = 0; u < 16; u += 4) {
      float4 k0 = kr[u], k1 = kr[u + 1], k2 = kr[u + 2], k3 = kr[u + 3];
      float4 q0 = *(const float4*)(qs + u * 4), q1 = *(const float4*)(qs + u * 4 + 4);
      float4 q2 = *(const float4*)(qs + u * 4 + 8), q3 = *(const float4*)(qs + u * 4 + 12);
      a0 = fmaf(q0.x, k0.x, a0); a0 = fmaf(q0.y, k0.y, a0); a0 = fmaf(q0.z, k0.z, a0); a0 = fmaf(q0.w, k0.w, a0);
      a1 = fmaf(q1.x, k1.x, a1); a1 = fmaf(q1.y, k1.y, a1); a1 = fmaf(q1.z, k1.z, a1); a1 = fmaf(q1.w, k1.w, a1);
      a2 = fmaf(q2.x, k2.x, a2); a2 = fmaf(q2.y, k2.y, a2); a2 = fmaf(q2.z, k2.z, a2); a2 = fmaf(q2.w, k2.w, a2);
      a3 = fmaf(q3.x, k3.x, a3); a3 = fmaf(q3.y, k3.y, a3); a3 = fmaf(q3.z, k3.z, a3); a3 = fmaf(q3.w, k3.w, a3);
    }
    float dot = (a0 + a1) + (a2 + a3);
    float d2 = fmaf(-2.f, dot, qnv + knorm[idx]);
    d2 = fmaxf(d2, 0.f);
    insert8(t, ((u64)__float_as_uint(d2) << 32) | (unsigned)idx);
  }
#pragma unroll
  for (int m = 1; m < 64; m <<= 1) {
    u64 o[8];
#pragma unroll
    for (int i = 0; i < 8; ++i) o[i] = shflx64(t[i], m);
    take8(t, o);
  }
  if (lane == 0) {
    float w8[8], s = 0.f;
#pragma unroll
    for (int i = 0; i < 8; ++i) {
      float d = __uint_as_float((unsigned)(t[i] >> 32));
      w8[i] = 1.f / (d + 1e-6f);
      s += w8[i];
    }
    conf[q] = w8[0];
#pragma unroll
    for (int i = 0; i < 8; ++i) {
      idxb[q * 8 + i] = (int)(unsigned)(t[i] & 0xffffffffull);
      wtsb[q * 8 + i] = w8[i] / s;
    }
  }
}

// ---------------- decoder layer 1: fused gather + K=64 GEMM + shared-context add ----------------
__global__ __launch_bounds__(256) void dec1_kernel(const float* __restrict__ keys,
                                                   const int* __restrict__ idxb,
                                                   const float* __restrict__ h1c,
                                                   const float* __restrict__ dw1,
                                                   const float* __restrict__ db1,
                                                   u16* __restrict__ h1d) {
  __shared__ float As[64][68];
  __shared__ float Bs[64][68];
  const int tid = threadIdx.x;
  const int tx = tid & 15, ty = tid >> 4;
  const int r0 = blockIdx.y * 64, c0 = blockIdx.x * 64;
  {
    const int row = tid >> 2, qd = tid & 3;
    const int id = idxb[r0 + row];
    const float4* kp = (const float4*)(keys + (size_t)id * 64 + qd * 16);
#pragma unroll
    for (int u = 0; u < 4; ++u) {
      float4 v = kp[u];
      As[qd * 16 + u * 4 + 0][row] = v.x;
      As[qd * 16 + u * 4 + 1][row] = v.y;
      As[qd * 16 + u * 4 + 2][row] = v.z;
      As[qd * 16 + u * 4 + 3][row] = v.w;
    }
  }
  {
    const int brr = tid >> 4, bcc = tid & 15;
#pragma unroll
    for (int p = 0; p < 4; ++p) {
      float4 v = *(const float4*)(dw1 + (size_t)(p * 16 + brr) * 256 + c0 + bcc * 4);
      *(float4*)(&Bs[p * 16 + brr][bcc * 4]) = v;
    }
  }
  __syncthreads();
  float acc[4][4] = {};
#pragma unroll
  for (int kk = 0; kk < 64; ++kk) {
    float4 av = *(const float4*)(&As[kk][ty * 4]);
    float4 bv = *(const float4*)(&Bs[kk][tx * 4]);
    float ar_[4] = {av.x, av.y, av.z, av.w};
    float br_[4] = {bv.x, bv.y, bv.z, bv.w};
#pragma unroll
    for (int i = 0; i < 4; ++i)
#pragma unroll
      for (int j = 0; j < 4; ++j) acc[i][j] = fmaf(ar_[i], br_[j], acc[i][j]);
  }
  float bb[4];
#pragma unroll
  for (int j = 0; j < 4; ++j) bb[j] = db1[c0 + tx * 4 + j];
#pragma unroll
  for (int i = 0; i < 4; ++i) {
    const int row = r0 + ty * 4 + i;
    const float4 hv = *(const float4*)(h1c + (size_t)(row >> 3) * 256 + c0 + tx * 4);
    ushort4 o;
    o.x = f2bf(gelu_f(acc[i][0] + hv.x + bb[0]));
    o.y = f2bf(gelu_f(acc[i][1] + hv.y + bb[1]));
    o.z = f2bf(gelu_f(acc[i][2] + hv.z + bb[2]));
    o.w = f2bf(gelu_f(acc[i][3] + hv.w + bb[3]));
    *(ushort4*)(h1d + (size_t)row * 256 + c0 + tx * 4) = o;
  }
}

// ---------------- bf16 MFMA GEMM: C = act(A[M,K] @ Wt[N,K]^T + bias) ----------------
// block 256 (4 waves), tile 128x128, BK=64; XOR-swizzled LDS (slot ^= row&7)
template <int ACT, int OUT_BF16>
__global__ __launch_bounds__(256) void gemm_mfma_kernel(const u16* __restrict__ A,
                                                        const u16* __restrict__ Bt,
                                                        const float* __restrict__ bias,
                                                        void* __restrict__ Cout,
                                                        int M, int N, int K) {
  __shared__ u16 As[128 * 64];
  __shared__ u16 Bs[128 * 64];
  const int tid = threadIdx.x;
  const int wave = tid >> 6, lane = tid & 63;
  const int g = lane >> 4, li = lane & 15;
  const int wr = wave >> 1, wc = wave & 1;
  const int m0 = blockIdx.y * 128, n0 = blockIdx.x * 128;
  f32x4 acc[4][4];
  f32x4 zz = {0.f, 0.f, 0.f, 0.f};
#pragma unroll
  for (int i = 0; i < 4; ++i)
#pragma unroll
    for (int j = 0; j < 4; ++j) acc[i][j] = zz;

  for (int k0 = 0; k0 < K; k0 += 64) {
    uint4 ra[4], rb[4];
#pragma unroll
    for (int i = 0; i < 4; ++i) {
      const int o = i * 4096 + tid * 16;           // byte offset in tile
      const int row = o >> 7;
      const int slot = (o >> 4) & 7;
      const int sk = ((slot ^ (row & 7)) << 3);    // source k-offset (elements)
      ra[i] = *(const uint4*)(A + (size_t)(m0 + row) * K + k0 + sk);
      rb[i] = *(const uint4*)(Bt + (size_t)(n0 + row) * K + k0 + sk);
    }
    __syncthreads();
#pragma unroll
    for (int i = 0; i < 4; ++i) {
      const int o = i * 4096 + tid * 16;
      *(uint4*)((char*)As + o) = ra[i];
      *(uint4*)((char*)Bs + o) = rb[i];
    }
    __syncthreads();
#pragma unroll
    for (int ko = 0; ko < 2; ++ko) {
      bf16x8 af[4], bf[4];
#pragma unroll
      for (int mi = 0; mi < 4; ++mi) {
        const int row = wr * 64 + mi * 16 + li;
        const int s = (ko * 4 + g) ^ (row & 7);
        af[mi] = *(const bf16x8*)((const char*)As + row * 128 + s * 16);
      }
#pragma unroll
      for (int ni = 0; ni < 4; ++ni) {
        const int row = wc * 64 + ni * 16 + li;
        const int s = (ko * 4 + g) ^ (row & 7);
        bf[ni] = *(const bf16x8*)((const char*)Bs + row * 128 + s * 16);
      }
#pragma unroll
      for (int mi = 0; mi < 4; ++mi)
#pragma unroll
        for (int ni = 0; ni < 4; ++ni)
          acc[mi][ni] = __builtin_amdgcn_mfma_f32_16x16x32_bf16(af[mi], bf[ni], acc[mi][ni], 0, 0, 0);
    }
    __syncthreads();
  }
  // epilogue: D row = 4g + reg, col = li (within 16x16 frag)
#pragma unroll
  for (int ni = 0; ni < 4; ++ni) {
    const int col = n0 + wc * 64 + ni * 16 + li;
    const float bb = bias[col];
#pragma unroll
    for (int mi = 0; mi < 4; ++mi) {
#pragma unroll
      for (int r = 0; r < 4; ++r) {
        const int row = m0 + wr * 64 + mi * 16 + g * 4 + r;
        float v = acc[mi][ni][r] + bb;
        if (ACT) v = gelu_f(v);
        if (OUT_BF16) ((u16*)Cout)[(size_t)row * N + col] = f2bf(v);
        else ((float*)Cout)[(size_t)row * N + col] = v;
      }
    }
  }
}

// ---------------- weighted combine ----------------
__global__ __launch_bounds__(256) void combine_kernel(const float* __restrict__ dec,
                                                      const float* __restrict__ wtsb,
                                                      float* __restrict__ out) {
  const int b = blockIdx.x, tid = threadIdx.x;
  float w[8];
#pragma unroll
  for (int i = 0; i < 8; ++i) w[i] = wtsb[b * 8 + i];
  const float4* d4 = (const float4*)(dec + (size_t)b * 8192);
  float4 acc = {0.f, 0.f, 0.f, 0.f};
#pragma unroll
  for (int i = 0; i < 8; ++i) {
    float4 v = d4[(size_t)i * 256 + tid];
    acc.x = fmaf(w[i], v.x, acc.x);
    acc.y = fmaf(w[i], v.y, acc.y);
    acc.z = fmaf(w[i], v.z, acc.z);
    acc.w = fmaf(w[i], v.w, acc.w);
  }
  ((float4*)out)[(size_t)b * 256 + tid] = acc;
}

extern "C" void kernel_launch(void* const* d_in, const int* in_sizes, int n_in,
                              void* d_out, int out_size, void* d_ws, size_t ws_size,
                              hipStream_t stream) {
  const float* query   = (const float*)d_in[0];
  const float* context = (const float*)d_in[1];
  const float* keys    = (const float*)d_in[2];
  const float* ew1 = (const float*)d_in[3];
  const float* eb1 = (const float*)d_in[4];
  const float* ew2 = (const float*)d_in[5];
  const float* eb2 = (const float*)d_in[6];
  const float* ew3 = (const float*)d_in[7];
  const float* eb3 = (const float*)d_in[8];
  const float* dw1 = (const float*)d_in[9];
  const float* db1 = (const float*)d_in[10];
  const float* dw2 = (const float*)d_in[11];
  const float* db2 = (const float*)d_in[12];
  const float* dw3 = (const float*)d_in[13];
  const float* db3 = (const float*)d_in[14];
  float* out = (float*)d_out;

  char* ws = (char*)d_ws;
  float* qc    = (float*)(ws + 0);          // 512*64*4          = 131072
  float* knorm = (float*)(ws + 131072);     // 100096*4          = 400384 (padded)
  u16*   qbf   = (u16*)  (ws + 531456);     // 512*64*2          = 65536
  float* qn    = (float*)(ws + 596992);     // 512*4 (+pad)      = 2048
  float* eh1   = (float*)(ws + 599040);     // 512*256*4         = 524288
  float* eh2   = (float*)(ws + 1123328);    // 512*128*4         = 262144
  int*   idxb  = (int*)  (ws + 1385472);    // 4096*4 (+pad)     = 16384
  float* wtsb  = (float*)(ws + 1401856);    // 4096*4 (+pad)     = 16384
  float* h1c   = (float*)(ws + 1418240);    // 512*256*4         = 524288
  u16*   kbf   = (u16*)  (ws + 1942528);    // 100096*64*2       = 12812288 (padded)
  u64*   cand  = (u64*)  (ws + 14754816);   // 512*64*8*8        = 2097152
  u16*   h1d   = (u16*)  (ws + 16851968);   // 4096*256*2 (+pad) = 2097152
  u16*   h2d   = (u16*)  (ws + 18949120);   // 4096*512*2        = 4194304
  u16*   w2t   = (u16*)  (ws + 23143424);   // 512*256*2         = 262144
  u16*   w3t   = (u16*)  (ws + 23405568);   // 1024*512*2        = 1048576
  float* dec   = (float*)(ws + 24454144);   // 4096*1024*4       = 16777216  (end: 41231360)

  // key norms + bf16 keys
  knormconv_kernel<<<dim3(391), dim3(256), 0, stream>>>(keys, knorm, kbf);

  // weight transposes -> bf16 [N][K]
  wconv_kernel<<<dim3(16, 8),  dim3(256), 0, stream>>>(dw2, w2t, 256, 512);
  wconv_kernel<<<dim3(32, 16), dim3(256), 0, stream>>>(dw3, w3t, 512, 1024);

  // encoder (fp32 exact: feeds top-k selection)
  gemm_kernel<1, 1><<<dim3(4, 8), dim3(256), 0, stream>>>(query, ew1, eb1, eh1, 512, 256, 1024);
  gemm_kernel<1, 1><<<dim3(2, 8), dim3(256), 0, stream>>>(eh1,   ew2, eb2, eh2, 512, 128, 256);
  gemm_kernel<0, 1><<<dim3(1, 8), dim3(256), 0, stream>>>(eh2,   ew3, eb3, qc,  512, 64,  128);
  qprep_kernel<<<dim3(2), dim3(256), 0, stream>>>(qc, qbf, qn);

  // shared context part of decoder layer 1 (fp32)
  gemm_kernel<0, 0><<<dim3(4, 8), dim3(256), 0, stream>>>(context, dw1 + (size_t)64 * 256, nullptr,
                                                          h1c, 512, 256, 1024);

  // MFMA approx distance scan -> per-chunk top-8; exact fp32 re-rank -> final top-8
  dist_scan_kernel<<<dim3(64, 8), dim3(256), 0, stream>>>(qbf, qn, kbf, knorm, cand);
  rerank_kernel<<<dim3(512), dim3(64), 0, stream>>>(cand, qc, qn, keys, knorm,
                                                    idxb, wtsb, out + 524288);

  // decoder
  dec1_kernel<<<dim3(4, 64), dim3(256), 0, stream>>>(keys, idxb, h1c, dw1, db1, h1d);
  gemm_mfma_kernel<1, 1><<<dim3(4, 32), dim3(256), 0, stream>>>(h1d, w2t, db2, h2d, 4096, 512, 256);
  gemm_mfma_kernel<0, 0><<<dim3(8, 32), dim3(256), 0, stream>>>(h2d, w3t, db3, dec, 4096, 1024, 512);

  // weighted combine
  combine_kernel<<<dim3(512), dim3(256), 0, stream>>>(dec, wtsb, out);
}

// Round 5
// 235.553 us; speedup vs baseline: 1.8506x; 1.8506x over previous
//
#include <hip/hip_runtime.h>

typedef unsigned long long u64;
typedef unsigned short u16;
typedef __bf16 bf16_t;
typedef bf16_t bf16x8 __attribute__((ext_vector_type(8)));
typedef float f32x4 __attribute__((ext_vector_type(4)));

#define DEVI __device__ __forceinline__

DEVI float gelu_f(float x) { return 0.5f * x * (1.0f + erff(x * 0.70710678f)); }

DEVI u16 f2bf(float x) {  // round-to-nearest-even f32 -> bf16
  unsigned u = __float_as_uint(x);
  return (u16)((u + 0x7fffu + ((u >> 16) & 1u)) >> 16);
}

DEVI void ce64(u64& a, u64& b) { u64 lo = a < b ? a : b; u64 hi = a < b ? b : a; a = lo; b = hi; }

DEVI u64 shflx64(u64 v, int m) {
  unsigned lo = (unsigned)__shfl_xor((int)(v & 0xffffffffull), m, 64);
  unsigned hi = (unsigned)__shfl_xor((int)(v >> 32), m, 64);
  return ((u64)hi << 32) | lo;
}

// t, o sorted ascending; t <- smallest 8 of union, sorted.
DEVI void take8(u64 t[8], const u64 o[8]) {
  u64 s[8];
#pragma unroll
  for (int i = 0; i < 8; ++i) { u64 x = o[7 - i]; s[i] = (t[i] < x) ? t[i] : x; }
  ce64(s[0], s[4]); ce64(s[1], s[5]); ce64(s[2], s[6]); ce64(s[3], s[7]);
  ce64(s[0], s[2]); ce64(s[1], s[3]); ce64(s[4], s[6]); ce64(s[5], s[7]);
  ce64(s[0], s[1]); ce64(s[2], s[3]); ce64(s[4], s[5]); ce64(s[6], s[7]);
#pragma unroll
  for (int i = 0; i < 8; ++i) t[i] = s[i];
}

// t, o sorted ascending (4); t <- smallest 4 of union, sorted.
DEVI void take4(u64 t[4], const u64 o[4]) {
  u64 s0 = t[0] < o[3] ? t[0] : o[3];
  u64 s1 = t[1] < o[2] ? t[1] : o[2];
  u64 s2 = t[2] < o[1] ? t[2] : o[1];
  u64 s3 = t[3] < o[0] ? t[3] : o[0];
  ce64(s0, s2); ce64(s1, s3); ce64(s0, s1); ce64(s2, s3);
  t[0] = s0; t[1] = s1; t[2] = s2; t[3] = s3;
}

DEVI void insert8(u64 t[8], u64 c) {
  if (c < t[7]) {
    t[7] = c;
    ce64(t[6], t[7]); ce64(t[5], t[6]); ce64(t[4], t[5]); ce64(t[3], t[4]);
    ce64(t[2], t[3]); ce64(t[1], t[2]); ce64(t[0], t[1]);
  }
}

// ================= fused preprocessing =================
// blocks [0,391): key norms + bf16 keys
// [391,519): w2t  (dw2 [256][512] -> [512][256] bf16)
// [519,1031): w3t (dw3 [512][1024] -> [1024][512] bf16)
// [1031,1287): w1ct (dw1[64:1088][256] -> [256][1024] bf16)
// [1287,1543): cbf (context fp32 -> bf16)
DEVI void wconv_body(float (*s)[33], const float* __restrict__ W, u16* __restrict__ Wt,
                     int K, int N, int bx, int by, int tid) {
  const int k0 = by * 32, n0 = bx * 32;
  const int a = tid >> 5, b2 = tid & 31;
#pragma unroll
  for (int p = 0; p < 4; ++p) s[a + p * 8][b2] = W[(size_t)(k0 + a + p * 8) * N + n0 + b2];
  __syncthreads();
#pragma unroll
  for (int p = 0; p < 4; ++p) Wt[(size_t)(n0 + a + p * 8) * K + k0 + b2] = f2bf(s[b2][a + p * 8]);
}

__global__ __launch_bounds__(256) void prep_kernel(const float* __restrict__ keys,
                                                   float* __restrict__ knorm,
                                                   u16* __restrict__ kbf,
                                                   const float* __restrict__ dw1,
                                                   u16* __restrict__ w1ct,
                                                   const float* __restrict__ dw2,
                                                   u16* __restrict__ w2t,
                                                   const float* __restrict__ dw3,
                                                   u16* __restrict__ w3t,
                                                   const float* __restrict__ context,
                                                   u16* __restrict__ cbf) {
  __shared__ float s[32][33];
  const int b = blockIdx.x, tid = threadIdx.x;
  if (b < 391) {
    int j = b * 256 + tid;
    if (j >= 100000) return;
    const float4* kp = (const float4*)(keys + (size_t)j * 64);
    u16* op = kbf + (size_t)j * 64;
    float a0 = 0.f, a1 = 0.f;
#pragma unroll
    for (int u = 0; u < 16; u += 2) {
      float4 v0 = kp[u], v1 = kp[u + 1];
      a0 = fmaf(v0.x, v0.x, a0); a0 = fmaf(v0.y, v0.y, a0); a0 = fmaf(v0.z, v0.z, a0); a0 = fmaf(v0.w, v0.w, a0);
      a1 = fmaf(v1.x, v1.x, a1); a1 = fmaf(v1.y, v1.y, a1); a1 = fmaf(v1.z, v1.z, a1); a1 = fmaf(v1.w, v1.w, a1);
      ushort4 o0 = {f2bf(v0.x), f2bf(v0.y), f2bf(v0.z), f2bf(v0.w)};
      ushort4 o1 = {f2bf(v1.x), f2bf(v1.y), f2bf(v1.z), f2bf(v1.w)};
      *(ushort4*)(op + u * 4) = o0;
      *(ushort4*)(op + u * 4 + 4) = o1;
    }
    knorm[j] = a0 + a1;
  } else if (b < 519) {
    int r = b - 391;
    wconv_body(s, dw2, w2t, 256, 512, r & 15, r >> 4, tid);
  } else if (b < 1031) {
    int r = b - 519;
    wconv_body(s, dw3, w3t, 512, 1024, r & 31, r >> 5, tid);
  } else if (b < 1287) {
    int r = b - 1031;
    wconv_body(s, dw1 + (size_t)64 * 256, w1ct, 1024, 256, r & 7, r >> 3, tid);
  } else {
    int r = b - 1287;
    size_t idx = ((size_t)r * 256 + tid) * 8;
    float4 v0 = *(const float4*)(context + idx);
    float4 v1 = *(const float4*)(context + idx + 4);
    uint4 o;
    o.x = (unsigned)f2bf(v0.x) | ((unsigned)f2bf(v0.y) << 16);
    o.y = (unsigned)f2bf(v0.z) | ((unsigned)f2bf(v0.w) << 16);
    o.z = (unsigned)f2bf(v1.x) | ((unsigned)f2bf(v1.y) << 16);
    o.w = (unsigned)f2bf(v1.z) | ((unsigned)f2bf(v1.w) << 16);
    *(uint4*)(cbf + idx) = o;
  }
}

// ================= fp32 GEMM, 32x32 tiles (encoder; k-order identical to prior rounds) =================
template <int ACT>
__global__ __launch_bounds__(256) void gemm32_kernel(const float* __restrict__ A,
                                                     const float* __restrict__ W,
                                                     const float* __restrict__ bias,
                                                     float* __restrict__ C,
                                                     int M, int N, int K) {
  __shared__ float As[32][33];
  __shared__ float Bs[32][36];
  const int tid = threadIdx.x;
  const int tx = tid & 7, ty = tid >> 3;
  const int row0 = blockIdx.y * 32, col0 = blockIdx.x * 32;
  float acc[4] = {0.f, 0.f, 0.f, 0.f};
  for (int k0 = 0; k0 < K; k0 += 32) {
    float4 a4 = *(const float4*)(A + (size_t)(row0 + ty) * K + k0 + tx * 4);
    float4 b4 = *(const float4*)(W + (size_t)(k0 + ty) * N + col0 + tx * 4);
    __syncthreads();
    As[tx * 4 + 0][ty] = a4.x;
    As[tx * 4 + 1][ty] = a4.y;
    As[tx * 4 + 2][ty] = a4.z;
    As[tx * 4 + 3][ty] = a4.w;
    *(float4*)(&Bs[ty][tx * 4]) = b4;
    __syncthreads();
#pragma unroll
    for (int kk = 0; kk < 32; ++kk) {
      float a = As[kk][ty];
      float4 bv = *(const float4*)(&Bs[kk][tx * 4]);
      acc[0] = fmaf(a, bv.x, acc[0]);
      acc[1] = fmaf(a, bv.y, acc[1]);
      acc[2] = fmaf(a, bv.z, acc[2]);
      acc[3] = fmaf(a, bv.w, acc[3]);
    }
  }
  float4 o;
  float b0 = bias[col0 + tx * 4 + 0], b1 = bias[col0 + tx * 4 + 1];
  float b2 = bias[col0 + tx * 4 + 2], b3 = bias[col0 + tx * 4 + 3];
  float v0 = acc[0] + b0, v1 = acc[1] + b1, v2 = acc[2] + b2, v3 = acc[3] + b3;
  if (ACT) { v0 = gelu_f(v0); v1 = gelu_f(v1); v2 = gelu_f(v2); v3 = gelu_f(v3); }
  o.x = v0; o.y = v1; o.z = v2; o.w = v3;
  *(float4*)(C + (size_t)(row0 + ty) * N + col0 + tx * 4) = o;
}

// ================= q -> bf16 + qnorm (identical math to round 3) =================
__global__ __launch_bounds__(256) void qprep_kernel(const float* __restrict__ qc,
                                                    u16* __restrict__ qbf,
                                                    float* __restrict__ qn) {
  int q = blockIdx.x * 256 + threadIdx.x;
  if (q >= 512) return;
  const float4* qp = (const float4*)(qc + (size_t)q * 64);
  u16* op = qbf + (size_t)q * 64;
  float s = 0.f;
#pragma unroll
  for (int u = 0; u < 16; ++u) {
    float4 v = qp[u];
    s = fmaf(v.x, v.x, fmaf(v.y, v.y, fmaf(v.z, v.z, fmaf(v.w, v.w, s))));
    ushort4 o = {f2bf(v.x), f2bf(v.y), f2bf(v.z), f2bf(v.w)};
    *(ushort4*)(op + u * 4) = o;
  }
  qn[q] = s;
}

// ================= bf16 MFMA GEMM, 64x64 tiles: C = act(A[M,K] @ Bt[N,K]^T + bias) =================
template <int ACT, int BIAS, int OUT_BF16>
__global__ __launch_bounds__(256) void mfma64_kernel(const u16* __restrict__ A,
                                                     const u16* __restrict__ Bt,
                                                     const float* __restrict__ bias,
                                                     void* __restrict__ Cout,
                                                     int M, int N, int K) {
  __shared__ u16 As[64 * 64];
  __shared__ u16 Bs[64 * 64];
  const int tid = threadIdx.x;
  const int wave = tid >> 6, lane = tid & 63;
  const int g = lane >> 4, li = lane & 15;
  const int wr = wave >> 1, wc = wave & 1;
  const int m0 = blockIdx.y * 64, n0 = blockIdx.x * 64;
  f32x4 acc[2][2];
  f32x4 zz = {0.f, 0.f, 0.f, 0.f};
#pragma unroll
  for (int i = 0; i < 2; ++i)
#pragma unroll
    for (int j = 0; j < 2; ++j) acc[i][j] = zz;

  const int o0 = tid * 16, o1 = o0 + 4096;
  const int r0s = o0 >> 7, s0 = (o0 >> 4) & 7;
  const int r1s = o1 >> 7, s1 = (o1 >> 4) & 7;
  const size_t a0off = (size_t)(m0 + r0s) * K + ((s0 ^ (r0s & 7)) << 3);
  const size_t a1off = (size_t)(m0 + r1s) * K + ((s1 ^ (r1s & 7)) << 3);
  const size_t b0off = (size_t)(n0 + r0s) * K + ((s0 ^ (r0s & 7)) << 3);
  const size_t b1off = (size_t)(n0 + r1s) * K + ((s1 ^ (r1s & 7)) << 3);

  for (int k0 = 0; k0 < K; k0 += 64) {
    uint4 ra0 = *(const uint4*)(A + a0off + k0);
    uint4 ra1 = *(const uint4*)(A + a1off + k0);
    uint4 rb0 = *(const uint4*)(Bt + b0off + k0);
    uint4 rb1 = *(const uint4*)(Bt + b1off + k0);
    __syncthreads();
    *(uint4*)((char*)As + o0) = ra0;
    *(uint4*)((char*)As + o1) = ra1;
    *(uint4*)((char*)Bs + o0) = rb0;
    *(uint4*)((char*)Bs + o1) = rb1;
    __syncthreads();
#pragma unroll
    for (int ko = 0; ko < 2; ++ko) {
      bf16x8 af[2], bfr[2];
#pragma unroll
      for (int mi = 0; mi < 2; ++mi) {
        const int row = wr * 32 + mi * 16 + li;
        const int sl = (ko * 4 + g) ^ (row & 7);
        af[mi] = *(const bf16x8*)((const char*)As + row * 128 + sl * 16);
      }
#pragma unroll
      for (int ni = 0; ni < 2; ++ni) {
        const int row = wc * 32 + ni * 16 + li;
        const int sl = (ko * 4 + g) ^ (row & 7);
        bfr[ni] = *(const bf16x8*)((const char*)Bs + row * 128 + sl * 16);
      }
#pragma unroll
      for (int mi = 0; mi < 2; ++mi)
#pragma unroll
        for (int ni = 0; ni < 2; ++ni)
          acc[mi][ni] = __builtin_amdgcn_mfma_f32_16x16x32_bf16(af[mi], bfr[ni], acc[mi][ni], 0, 0, 0);
    }
  }
#pragma unroll
  for (int ni = 0; ni < 2; ++ni) {
    const int col = n0 + wc * 32 + ni * 16 + li;
    const float bb = BIAS ? bias[col] : 0.f;
#pragma unroll
    for (int mi = 0; mi < 2; ++mi) {
#pragma unroll
      for (int r = 0; r < 4; ++r) {
        const int row = m0 + wr * 32 + mi * 16 + g * 4 + r;
        float v = acc[mi][ni][r] + bb;
        if (ACT) v = gelu_f(v);
        if (OUT_BF16) ((u16*)Cout)[(size_t)row * N + col] = f2bf(v);
        else ((float*)Cout)[(size_t)row * N + col] = v;
      }
    }
  }
}

// ================= MFMA distance scan: per-(query,chunk) top-4 =================
// grid (256 chunks, 8 q-tiles), block 256 (4 waves, wave = 16 queries)
// t[] init packs d2=+inf (NOT ~0ull): ~0ull's hi bits are NaN, which poisons
// the thr fast-path (NaN comparison rejects everything after first insert).
__global__ __launch_bounds__(256) void dist_scan_kernel(const u16* __restrict__ qbf,
                                                        const float* __restrict__ qn,
                                                        const u16* __restrict__ kbf,
                                                        const float* __restrict__ knorm,
                                                        u64* __restrict__ cand) {
  const int NKEYS = 100000, CK = 391, NCH = 256;
  const int tid = threadIdx.x;
  const int wave = tid >> 6, lane = tid & 63;
  const int g = lane >> 4, qi = lane & 15;
  const int qrow = blockIdx.y * 64 + wave * 16 + qi;
  const bf16x8 b0 = *(const bf16x8*)(qbf + (size_t)qrow * 64 + g * 8);
  const bf16x8 b1 = *(const bf16x8*)(qbf + (size_t)qrow * 64 + 32 + g * 8);
  const float qnv = qn[qrow];
  u64 t[4];
#pragma unroll
  for (int i = 0; i < 4; ++i) t[i] = 0x7F800000FFFFFFFFull;  // d2=+inf, idx=sentinel
  float thr = 3.4e38f;
  const int c0 = blockIdx.x * CK;
  const int c1 = (c0 + CK < NKEYS) ? c0 + CK : NKEYS;
  for (int kt = c0; kt < c1; kt += 16) {
    const u16* kp = kbf + (size_t)(kt + qi) * 64 + g * 8;
    bf16x8 a0 = *(const bf16x8*)(kp);
    bf16x8 a1 = *(const bf16x8*)(kp + 32);
    f32x4 zz = {0.f, 0.f, 0.f, 0.f};
    f32x4 acc = __builtin_amdgcn_mfma_f32_16x16x32_bf16(a0, b0, zz, 0, 0, 0);
    acc = __builtin_amdgcn_mfma_f32_16x16x32_bf16(a1, b1, acc, 0, 0, 0);
    const float4 kn4 = *(const float4*)(knorm + kt + g * 4);
    const float knr[4] = {kn4.x, kn4.y, kn4.z, kn4.w};
    const int kbase = kt + g * 4;
#pragma unroll
    for (int r = 0; r < 4; ++r) {
      const int kidx = kbase + r;
      const float s = fmaf(-2.f, acc[r], knr[r]);
      if (s <= thr && kidx < c1) {  // rare after the first 4 inserts
        float d2 = fmaxf(s + qnv, 0.f);
        u64 c = ((u64)__float_as_uint(d2) << 32) | (unsigned)kidx;
        if (c < t[3]) {
          t[3] = c;
          ce64(t[2], t[3]); ce64(t[1], t[2]); ce64(t[0], t[1]);
        }
        thr = __uint_as_float((unsigned)(t[3] >> 32)) - qnv;
      }
    }
  }
  // merge the 4 lane-groups sharing this query -> chunk top-4
  {
    u64 o[4];
#pragma unroll
    for (int i = 0; i < 4; ++i) o[i] = shflx64(t[i], 16);
    take4(t, o);
#pragma unroll
    for (int i = 0; i < 4; ++i) o[i] = shflx64(t[i], 32);
    take4(t, o);
  }
  if (lane < 16) {
    u64* cp = cand + ((size_t)qrow * NCH + blockIdx.x) * 4;
#pragma unroll
    for (int i = 0; i < 4; ++i) cp[i] = t[i];
  }
}

// ================= merge 256 chunk-top-4 lists -> 4 quarter-top-8s = 32 candidates =================
__global__ __launch_bounds__(256) void merge_kernel(const u64* __restrict__ cand,
                                                    int* __restrict__ cand32) {
  const int q = blockIdx.x * 4 + (threadIdx.x >> 6);
  const int lane = threadIdx.x & 63;
  u64 t[8];
#pragma unroll
  for (int i = 0; i < 8; ++i) t[i] = ~0ull;
  const u64* cp = cand + (size_t)q * 1024 + (size_t)lane * 16;
#pragma unroll
  for (int i = 0; i < 16; ++i) insert8(t, cp[i]);
#pragma unroll
  for (int m = 1; m < 16; m <<= 1) {
    u64 o[8];
#pragma unroll
    for (int i = 0; i < 8; ++i) o[i] = shflx64(t[i], m);
    take8(t, o);
  }
  if ((lane & 15) == 0) {
    int* op = cand32 + q * 32 + (lane >> 4) * 8;
#pragma unroll
    for (int i = 0; i < 8; ++i) op[i] = (int)(unsigned)(t[i] & 0xffffffffull);
  }
}

// ================= exact fp32 re-rank of 32 candidates -> final top-8 =================
__global__ __launch_bounds__(256) void rerank_kernel(const int* __restrict__ cand32,
                                                     const float* __restrict__ qc,
                                                     const float* __restrict__ qn,
                                                     const float* __restrict__ keys,
                                                     const float* __restrict__ knorm,
                                                     int* __restrict__ idxb,
                                                     float* __restrict__ wtsb,
                                                     float* __restrict__ conf) {
  const int sub = threadIdx.x >> 6, lane = threadIdx.x & 63;
  const int q = blockIdx.x * 4 + sub;
  __shared__ float qs[4][64];
  if (lane < 16) *(float4*)(&qs[sub][lane * 4]) = ((const float4*)(qc + (size_t)q * 64))[lane];
  __syncthreads();
  u64 t[8];
#pragma unroll
  for (int i = 0; i < 8; ++i) t[i] = ~0ull;
  if (lane < 32) {
    const int idx = cand32[q * 32 + lane];
    if ((unsigned)idx < 100000u) {
      const float4* kr = (const float4*)(keys + (size_t)idx * 64);
      float a0 = 0.f, a1 = 0.f, a2 = 0.f, a3 = 0.f;
#pragma unroll
      for (int u = 0; u < 16; u += 4) {
        float4 k0 = kr[u], k1 = kr[u + 1], k2 = kr[u + 2], k3 = kr[u + 3];
        float4 q0 = *(const float4*)(&qs[sub][u * 4]), q1 = *(const float4*)(&qs[sub][u * 4 + 4]);
        float4 q2 = *(const float4*)(&qs[sub][u * 4 + 8]), q3 = *(const float4*)(&qs[sub][u * 4 + 12]);
        a0 = fmaf(q0.x, k0.x, a0); a0 = fmaf(q0.y, k0.y, a0); a0 = fmaf(q0.z, k0.z, a0); a0 = fmaf(q0.w, k0.w, a0);
        a1 = fmaf(q1.x, k1.x, a1); a1 = fmaf(q1.y, k1.y, a1); a1 = fmaf(q1.z, k1.z, a1); a1 = fmaf(q1.w, k1.w, a1);
        a2 = fmaf(q2.x, k2.x, a2); a2 = fmaf(q2.y, k2.y, a2); a2 = fmaf(q2.z, k2.z, a2); a2 = fmaf(q2.w, k2.w, a2);
        a3 = fmaf(q3.x, k3.x, a3); a3 = fmaf(q3.y, k3.y, a3); a3 = fmaf(q3.z, k3.z, a3); a3 = fmaf(q3.w, k3.w, a3);
      }
      float dot = (a0 + a1) + (a2 + a3);
      float d2 = fmaf(-2.f, dot, qn[q] + knorm[idx]);
      d2 = fmaxf(d2, 0.f);
      t[0] = ((u64)__float_as_uint(d2) << 32) | (unsigned)idx;
    }
  }
#pragma unroll
  for (int m = 1; m < 64; m <<= 1) {
    u64 o[8];
#pragma unroll
    for (int i = 0; i < 8; ++i) o[i] = shflx64(t[i], m);
    take8(t, o);
  }
  if (lane == 0) {
    float w8[8], s = 0.f;
#pragma unroll
    for (int i = 0; i < 8; ++i) {
      float d = __uint_as_float((unsigned)(t[i] >> 32));
      w8[i] = 1.f / (d + 1e-6f);
      s += w8[i];
    }
    conf[q] = w8[0];
#pragma unroll
    for (int i = 0; i < 8; ++i) {
      idxb[q * 8 + i] = (int)(unsigned)(t[i] & 0xffffffffull);
      wtsb[q * 8 + i] = w8[i] / s;
    }
  }
}

// ================= decoder layer 1: fused gather + K=64 GEMM + shared-context add =================
__global__ __launch_bounds__(256) void dec1_kernel(const float* __restrict__ keys,
                                                   const int* __restrict__ idxb,
                                                   const float* __restrict__ h1c,
                                                   const float* __restrict__ dw1,
                                                   const float* __restrict__ db1,
                                                   u16* __restrict__ h1d) {
  __shared__ float As[64][68];
  __shared__ float Bs[64][68];
  const int tid = threadIdx.x;
  const int tx = tid & 15, ty = tid >> 4;
  const int r0 = blockIdx.y * 64, c0 = blockIdx.x * 64;
  {
    const int row = tid >> 2, qd = tid & 3;
    const int id = idxb[r0 + row];
    const float4* kp = (const float4*)(keys + (size_t)id * 64 + qd * 16);
#pragma unroll
    for (int u = 0; u < 4; ++u) {
      float4 v = kp[u];
      As[qd * 16 + u * 4 + 0][row] = v.x;
      As[qd * 16 + u * 4 + 1][row] = v.y;
      As[qd * 16 + u * 4 + 2][row] = v.z;
      As[qd * 16 + u * 4 + 3][row] = v.w;
    }
  }
  {
    const int brr = tid >> 4, bcc = tid & 15;
#pragma unroll
    for (int p = 0; p < 4; ++p) {
      float4 v = *(const float4*)(dw1 + (size_t)(p * 16 + brr) * 256 + c0 + bcc * 4);
      *(float4*)(&Bs[p * 16 + brr][bcc * 4]) = v;
    }
  }
  __syncthreads();
  float acc[4][4] = {};
#pragma unroll
  for (int kk = 0; kk < 64; ++kk) {
    float4 av = *(const float4*)(&As[kk][ty * 4]);
    float4 bv = *(const float4*)(&Bs[kk][tx * 4]);
    float ar_[4] = {av.x, av.y, av.z, av.w};
    float br_[4] = {bv.x, bv.y, bv.z, bv.w};
#pragma unroll
    for (int i = 0; i < 4; ++i)
#pragma unroll
      for (int j = 0; j < 4; ++j) acc[i][j] = fmaf(ar_[i], br_[j], acc[i][j]);
  }
  float bb[4];
#pragma unroll
  for (int j = 0; j < 4; ++j) bb[j] = db1[c0 + tx * 4 + j];
#pragma unroll
  for (int i = 0; i < 4; ++i) {
    const int row = r0 + ty * 4 + i;
    const float4 hv = *(const float4*)(h1c + (size_t)(row >> 3) * 256 + c0 + tx * 4);
    ushort4 o;
    o.x = f2bf(gelu_f(acc[i][0] + hv.x + bb[0]));
    o.y = f2bf(gelu_f(acc[i][1] + hv.y + bb[1]));
    o.z = f2bf(gelu_f(acc[i][2] + hv.z + bb[2]));
    o.w = f2bf(gelu_f(acc[i][3] + hv.w + bb[3]));
    *(ushort4*)(h1d + (size_t)row * 256 + c0 + tx * 4) = o;
  }
}

// ================= weighted combine =================
__global__ __launch_bounds__(256) void combine_kernel(const float* __restrict__ dec,
                                                      const float* __restrict__ wtsb,
                                                      float* __restrict__ out) {
  const int b = blockIdx.x, tid = threadIdx.x;
  float w[8];
#pragma unroll
  for (int i = 0; i < 8; ++i) w[i] = wtsb[b * 8 + i];
  const float4* d4 = (const float4*)(dec + (size_t)b * 8192);
  float4 acc = {0.f, 0.f, 0.f, 0.f};
#pragma unroll
  for (int i = 0; i < 8; ++i) {
    float4 v = d4[(size_t)i * 256 + tid];
    acc.x = fmaf(w[i], v.x, acc.x);
    acc.y = fmaf(w[i], v.y, acc.y);
    acc.z = fmaf(w[i], v.z, acc.z);
    acc.w = fmaf(w[i], v.w, acc.w);
  }
  ((float4*)out)[(size_t)b * 256 + tid] = acc;
}

extern "C" void kernel_launch(void* const* d_in, const int* in_sizes, int n_in,
                              void* d_out, int out_size, void* d_ws, size_t ws_size,
                              hipStream_t stream) {
  const float* query   = (const float*)d_in[0];
  const float* context = (const float*)d_in[1];
  const float* keys    = (const float*)d_in[2];
  const float* ew1 = (const float*)d_in[3];
  const float* eb1 = (const float*)d_in[4];
  const float* ew2 = (const float*)d_in[5];
  const float* eb2 = (const float*)d_in[6];
  const float* ew3 = (const float*)d_in[7];
  const float* eb3 = (const float*)d_in[8];
  const float* dw1 = (const float*)d_in[9];
  const float* db1 = (const float*)d_in[10];
  const float* dw2 = (const float*)d_in[11];
  const float* db2 = (const float*)d_in[12];
  const float* dw3 = (const float*)d_in[13];
  const float* db3 = (const float*)d_in[14];
  float* out = (float*)d_out;

  char* ws = (char*)d_ws;
  float* qc     = (float*)(ws + 0);          // 131072
  float* knorm  = (float*)(ws + 131072);     // 100096*4 = 400384
  u16*   qbf    = (u16*)  (ws + 531456);     // 65536
  float* qn     = (float*)(ws + 596992);     // 2048
  float* eh1    = (float*)(ws + 599040);     // 524288
  float* eh2    = (float*)(ws + 1123328);    // 262144
  int*   idxb   = (int*)  (ws + 1385472);    // 16384
  float* wtsb   = (float*)(ws + 1401856);    // 16384
  float* h1c    = (float*)(ws + 1418240);    // 524288
  u16*   kbf    = (u16*)  (ws + 1942528);    // 100096*64*2 = 12812288
  u64*   cand   = (u64*)  (ws + 14754816);   // 512*256*4*8 = 4194304 (dies after merge)
  float* dec    = (float*)(ws + 14754816);   // 4096*1024*4 = 16777216 (aliases cand; written after rerank)
  int*   cand32 = (int*)  (ws + 31532032);   // 512*32*4 = 65536
  u16*   h1d    = (u16*)  (ws + 31597568);   // 4096*256*2 = 2097152
  u16*   h2d    = (u16*)  (ws + 33694720);   // 4096*512*2 = 4194304
  u16*   w2t    = (u16*)  (ws + 37889024);   // 512*256*2 = 262144
  u16*   w3t    = (u16*)  (ws + 38151168);   // 1024*512*2 = 1048576
  u16*   w1ct   = (u16*)  (ws + 39199744);   // 256*1024*2 = 524288
  u16*   cbf    = (u16*)  (ws + 39724032);   // 512*1024*2 = 1048576   (end 40772608)

  // fused preprocessing: knorm+kbf, w2t, w3t, w1ct, cbf
  prep_kernel<<<dim3(1543), dim3(256), 0, stream>>>(keys, knorm, kbf, dw1, w1ct, dw2, w2t,
                                                    dw3, w3t, context, cbf);

  // encoder (fp32 exact, bit-identical k-order to prior passing rounds)
  gemm32_kernel<1><<<dim3(8, 16), dim3(256), 0, stream>>>(query, ew1, eb1, eh1, 512, 256, 1024);
  gemm32_kernel<1><<<dim3(4, 16), dim3(256), 0, stream>>>(eh1,   ew2, eb2, eh2, 512, 128, 256);
  gemm32_kernel<0><<<dim3(2, 16), dim3(256), 0, stream>>>(eh2,   ew3, eb3, qc,  512, 64,  128);
  qprep_kernel<<<dim3(2), dim3(256), 0, stream>>>(qc, qbf, qn);

  // shared context part of decoder layer 1 (bf16 MFMA; decode path only)
  mfma64_kernel<0, 0, 0><<<dim3(4, 8), dim3(256), 0, stream>>>(cbf, w1ct, nullptr, h1c,
                                                               512, 256, 1024);

  // selection: MFMA scan (per-chunk top-4) -> merge (32 survivors) -> exact fp32 rerank
  dist_scan_kernel<<<dim3(256, 8), dim3(256), 0, stream>>>(qbf, qn, kbf, knorm, cand);
  merge_kernel<<<dim3(128), dim3(256), 0, stream>>>(cand, cand32);
  rerank_kernel<<<dim3(128), dim3(256), 0, stream>>>(cand32, qc, qn, keys, knorm,
                                                     idxb, wtsb, out + 524288);

  // decoder
  dec1_kernel<<<dim3(4, 64), dim3(256), 0, stream>>>(keys, idxb, h1c, dw1, db1, h1d);
  mfma64_kernel<1, 1, 1><<<dim3(8, 64),  dim3(256), 0, stream>>>(h1d, w2t, db2, h2d, 4096, 512, 256);
  mfma64_kernel<0, 1, 0><<<dim3(16, 64), dim3(256), 0, stream>>>(h2d, w3t, db3, dec, 4096, 1024, 512);

  // weighted combine
  combine_kernel<<<dim3(512), dim3(256), 0, stream>>>(dec, wtsb, out);
}

// Round 6
// 178.465 us; speedup vs baseline: 2.4426x; 1.3199x over previous
//
#include <hip/hip_runtime.h>

typedef unsigned long long u64;
typedef unsigned short u16;
typedef __bf16 bf16_t;
typedef bf16_t bf16x8 __attribute__((ext_vector_type(8)));
typedef float f32x4 __attribute__((ext_vector_type(4)));

#define DEVI __device__ __forceinline__

DEVI float gelu_f(float x) { return 0.5f * x * (1.0f + erff(x * 0.70710678f)); }

DEVI u16 f2bf(float x) {  // round-to-nearest-even f32 -> bf16
  unsigned u = __float_as_uint(x);
  return (u16)((u + 0x7fffu + ((u >> 16) & 1u)) >> 16);
}

DEVI void ce64(u64& a, u64& b) { u64 lo = a < b ? a : b; u64 hi = a < b ? b : a; a = lo; b = hi; }

DEVI u64 shflx64(u64 v, int m) {
  unsigned lo = (unsigned)__shfl_xor((int)(v & 0xffffffffull), m, 64);
  unsigned hi = (unsigned)__shfl_xor((int)(v >> 32), m, 64);
  return ((u64)hi << 32) | lo;
}

// t, o sorted ascending; t <- smallest 8 of union, sorted.
DEVI void take8(u64 t[8], const u64 o[8]) {
  u64 s[8];
#pragma unroll
  for (int i = 0; i < 8; ++i) { u64 x = o[7 - i]; s[i] = (t[i] < x) ? t[i] : x; }
  ce64(s[0], s[4]); ce64(s[1], s[5]); ce64(s[2], s[6]); ce64(s[3], s[7]);
  ce64(s[0], s[2]); ce64(s[1], s[3]); ce64(s[4], s[6]); ce64(s[5], s[7]);
  ce64(s[0], s[1]); ce64(s[2], s[3]); ce64(s[4], s[5]); ce64(s[6], s[7]);
#pragma unroll
  for (int i = 0; i < 8; ++i) t[i] = s[i];
}

// t, o sorted ascending (4); t <- smallest 4 of union, sorted.
DEVI void take4(u64 t[4], const u64 o[4]) {
  u64 s0 = t[0] < o[3] ? t[0] : o[3];
  u64 s1 = t[1] < o[2] ? t[1] : o[2];
  u64 s2 = t[2] < o[1] ? t[2] : o[1];
  u64 s3 = t[3] < o[0] ? t[3] : o[0];
  ce64(s0, s2); ce64(s1, s3); ce64(s0, s1); ce64(s2, s3);
  t[0] = s0; t[1] = s1; t[2] = s2; t[3] = s3;
}

DEVI void insert8(u64 t[8], u64 c) {
  if (c < t[7]) {
    t[7] = c;
    ce64(t[6], t[7]); ce64(t[5], t[6]); ce64(t[4], t[5]); ce64(t[3], t[4]);
    ce64(t[2], t[3]); ce64(t[1], t[2]); ce64(t[0], t[1]);
  }
}

// ================= fused preprocessing =================
// blocks [0,391): key norms + bf16 keys
// [391,519): w2t  (dw2 [256][512] -> [512][256] bf16)
// [519,1031): w3t (dw3 [512][1024] -> [1024][512] bf16)
// [1031,1287): w1ct (dw1[64:1088][256] -> [256][1024] bf16)
// [1287,1543): cbf (context fp32 -> bf16)
// [1543,1559): w1kt (dw1[0:64][256] -> [256][64] bf16)
DEVI void wconv_body(float (*s)[33], const float* __restrict__ W, u16* __restrict__ Wt,
                     int K, int N, int bx, int by, int tid) {
  const int k0 = by * 32, n0 = bx * 32;
  const int a = tid >> 5, b2 = tid & 31;
#pragma unroll
  for (int p = 0; p < 4; ++p) s[a + p * 8][b2] = W[(size_t)(k0 + a + p * 8) * N + n0 + b2];
  __syncthreads();
#pragma unroll
  for (int p = 0; p < 4; ++p) Wt[(size_t)(n0 + a + p * 8) * K + k0 + b2] = f2bf(s[b2][a + p * 8]);
}

__global__ __launch_bounds__(256) void prep_kernel(const float* __restrict__ keys,
                                                   float* __restrict__ knorm,
                                                   u16* __restrict__ kbf,
                                                   const float* __restrict__ dw1,
                                                   u16* __restrict__ w1ct,
                                                   u16* __restrict__ w1kt,
                                                   const float* __restrict__ dw2,
                                                   u16* __restrict__ w2t,
                                                   const float* __restrict__ dw3,
                                                   u16* __restrict__ w3t,
                                                   const float* __restrict__ context,
                                                   u16* __restrict__ cbf) {
  __shared__ float s[32][33];
  const int b = blockIdx.x, tid = threadIdx.x;
  if (b < 391) {
    int j = b * 256 + tid;
    if (j >= 100000) return;
    const float4* kp = (const float4*)(keys + (size_t)j * 64);
    u16* op = kbf + (size_t)j * 64;
    float a0 = 0.f, a1 = 0.f;
#pragma unroll
    for (int u = 0; u < 16; u += 2) {
      float4 v0 = kp[u], v1 = kp[u + 1];
      a0 = fmaf(v0.x, v0.x, a0); a0 = fmaf(v0.y, v0.y, a0); a0 = fmaf(v0.z, v0.z, a0); a0 = fmaf(v0.w, v0.w, a0);
      a1 = fmaf(v1.x, v1.x, a1); a1 = fmaf(v1.y, v1.y, a1); a1 = fmaf(v1.z, v1.z, a1); a1 = fmaf(v1.w, v1.w, a1);
      ushort4 o0 = {f2bf(v0.x), f2bf(v0.y), f2bf(v0.z), f2bf(v0.w)};
      ushort4 o1 = {f2bf(v1.x), f2bf(v1.y), f2bf(v1.z), f2bf(v1.w)};
      *(ushort4*)(op + u * 4) = o0;
      *(ushort4*)(op + u * 4 + 4) = o1;
    }
    knorm[j] = a0 + a1;
  } else if (b < 519) {
    int r = b - 391;
    wconv_body(s, dw2, w2t, 256, 512, r & 15, r >> 4, tid);
  } else if (b < 1031) {
    int r = b - 519;
    wconv_body(s, dw3, w3t, 512, 1024, r & 31, r >> 5, tid);
  } else if (b < 1287) {
    int r = b - 1031;
    wconv_body(s, dw1 + (size_t)64 * 256, w1ct, 1024, 256, r & 7, r >> 3, tid);
  } else if (b < 1543) {
    int r = b - 1287;
    size_t idx = ((size_t)r * 256 + tid) * 8;
    float4 v0 = *(const float4*)(context + idx);
    float4 v1 = *(const float4*)(context + idx + 4);
    uint4 o;
    o.x = (unsigned)f2bf(v0.x) | ((unsigned)f2bf(v0.y) << 16);
    o.y = (unsigned)f2bf(v0.z) | ((unsigned)f2bf(v0.w) << 16);
    o.z = (unsigned)f2bf(v1.x) | ((unsigned)f2bf(v1.y) << 16);
    o.w = (unsigned)f2bf(v1.z) | ((unsigned)f2bf(v1.w) << 16);
    *(uint4*)(cbf + idx) = o;
  } else {
    int r = b - 1543;  // [0,16): transpose dw1[0:64][256] -> w1kt[256][64]
    wconv_body(s, dw1, w1kt, 64, 256, r & 7, r >> 3, tid);
  }
}

// ================= fp32 GEMM, 32x32 tiles (encoder; k-order identical to prior rounds) =================
template <int ACT>
__global__ __launch_bounds__(256) void gemm32_kernel(const float* __restrict__ A,
                                                     const float* __restrict__ W,
                                                     const float* __restrict__ bias,
                                                     float* __restrict__ C,
                                                     int M, int N, int K) {
  __shared__ float As[32][33];
  __shared__ float Bs[32][36];
  const int tid = threadIdx.x;
  const int tx = tid & 7, ty = tid >> 3;
  const int row0 = blockIdx.y * 32, col0 = blockIdx.x * 32;
  float acc[4] = {0.f, 0.f, 0.f, 0.f};
  for (int k0 = 0; k0 < K; k0 += 32) {
    float4 a4 = *(const float4*)(A + (size_t)(row0 + ty) * K + k0 + tx * 4);
    float4 b4 = *(const float4*)(W + (size_t)(k0 + ty) * N + col0 + tx * 4);
    __syncthreads();
    As[tx * 4 + 0][ty] = a4.x;
    As[tx * 4 + 1][ty] = a4.y;
    As[tx * 4 + 2][ty] = a4.z;
    As[tx * 4 + 3][ty] = a4.w;
    *(float4*)(&Bs[ty][tx * 4]) = b4;
    __syncthreads();
#pragma unroll
    for (int kk = 0; kk < 32; ++kk) {
      float a = As[kk][ty];
      float4 bv = *(const float4*)(&Bs[kk][tx * 4]);
      acc[0] = fmaf(a, bv.x, acc[0]);
      acc[1] = fmaf(a, bv.y, acc[1]);
      acc[2] = fmaf(a, bv.z, acc[2]);
      acc[3] = fmaf(a, bv.w, acc[3]);
    }
  }
  float4 o;
  float b0 = bias[col0 + tx * 4 + 0], b1 = bias[col0 + tx * 4 + 1];
  float b2 = bias[col0 + tx * 4 + 2], b3 = bias[col0 + tx * 4 + 3];
  float v0 = acc[0] + b0, v1 = acc[1] + b1, v2 = acc[2] + b2, v3 = acc[3] + b3;
  if (ACT) { v0 = gelu_f(v0); v1 = gelu_f(v1); v2 = gelu_f(v2); v3 = gelu_f(v3); }
  o.x = v0; o.y = v1; o.z = v2; o.w = v3;
  *(float4*)(C + (size_t)(row0 + ty) * N + col0 + tx * 4) = o;
}

// ================= q -> bf16 + qnorm =================
__global__ __launch_bounds__(256) void qprep_kernel(const float* __restrict__ qc,
                                                    u16* __restrict__ qbf,
                                                    float* __restrict__ qn) {
  int q = blockIdx.x * 256 + threadIdx.x;
  if (q >= 512) return;
  const float4* qp = (const float4*)(qc + (size_t)q * 64);
  u16* op = qbf + (size_t)q * 64;
  float s = 0.f;
#pragma unroll
  for (int u = 0; u < 16; ++u) {
    float4 v = qp[u];
    s = fmaf(v.x, v.x, fmaf(v.y, v.y, fmaf(v.z, v.z, fmaf(v.w, v.w, s))));
    ushort4 o = {f2bf(v.x), f2bf(v.y), f2bf(v.z), f2bf(v.w)};
    *(ushort4*)(op + u * 4) = o;
  }
  qn[q] = s;
}

// ================= bf16 MFMA GEMM, 64x64 tiles: C = act(A[M,K] @ Bt[N,K]^T + bias) =================
template <int ACT, int BIAS, int OUT_BF16>
__global__ __launch_bounds__(256) void mfma64_kernel(const u16* __restrict__ A,
                                                     const u16* __restrict__ Bt,
                                                     const float* __restrict__ bias,
                                                     void* __restrict__ Cout,
                                                     int M, int N, int K) {
  __shared__ u16 As[64 * 64];
  __shared__ u16 Bs[64 * 64];
  const int tid = threadIdx.x;
  const int wave = tid >> 6, lane = tid & 63;
  const int g = lane >> 4, li = lane & 15;
  const int wr = wave >> 1, wc = wave & 1;
  const int m0 = blockIdx.y * 64, n0 = blockIdx.x * 64;
  f32x4 acc[2][2];
  f32x4 zz = {0.f, 0.f, 0.f, 0.f};
#pragma unroll
  for (int i = 0; i < 2; ++i)
#pragma unroll
    for (int j = 0; j < 2; ++j) acc[i][j] = zz;

  const int o0 = tid * 16, o1 = o0 + 4096;
  const int r0s = o0 >> 7, s0 = (o0 >> 4) & 7;
  const int r1s = o1 >> 7, s1 = (o1 >> 4) & 7;
  const size_t a0off = (size_t)(m0 + r0s) * K + ((s0 ^ (r0s & 7)) << 3);
  const size_t a1off = (size_t)(m0 + r1s) * K + ((s1 ^ (r1s & 7)) << 3);
  const size_t b0off = (size_t)(n0 + r0s) * K + ((s0 ^ (r0s & 7)) << 3);
  const size_t b1off = (size_t)(n0 + r1s) * K + ((s1 ^ (r1s & 7)) << 3);

  for (int k0 = 0; k0 < K; k0 += 64) {
    uint4 ra0 = *(const uint4*)(A + a0off + k0);
    uint4 ra1 = *(const uint4*)(A + a1off + k0);
    uint4 rb0 = *(const uint4*)(Bt + b0off + k0);
    uint4 rb1 = *(const uint4*)(Bt + b1off + k0);
    __syncthreads();
    *(uint4*)((char*)As + o0) = ra0;
    *(uint4*)((char*)As + o1) = ra1;
    *(uint4*)((char*)Bs + o0) = rb0;
    *(uint4*)((char*)Bs + o1) = rb1;
    __syncthreads();
#pragma unroll
    for (int ko = 0; ko < 2; ++ko) {
      bf16x8 af[2], bfr[2];
#pragma unroll
      for (int mi = 0; mi < 2; ++mi) {
        const int row = wr * 32 + mi * 16 + li;
        const int sl = (ko * 4 + g) ^ (row & 7);
        af[mi] = *(const bf16x8*)((const char*)As + row * 128 + sl * 16);
      }
#pragma unroll
      for (int ni = 0; ni < 2; ++ni) {
        const int row = wc * 32 + ni * 16 + li;
        const int sl = (ko * 4 + g) ^ (row & 7);
        bfr[ni] = *(const bf16x8*)((const char*)Bs + row * 128 + sl * 16);
      }
#pragma unroll
      for (int mi = 0; mi < 2; ++mi)
#pragma unroll
        for (int ni = 0; ni < 2; ++ni)
          acc[mi][ni] = __builtin_amdgcn_mfma_f32_16x16x32_bf16(af[mi], bfr[ni], acc[mi][ni], 0, 0, 0);
    }
  }
#pragma unroll
  for (int ni = 0; ni < 2; ++ni) {
    const int col = n0 + wc * 32 + ni * 16 + li;
    const float bb = BIAS ? bias[col] : 0.f;
#pragma unroll
    for (int mi = 0; mi < 2; ++mi) {
#pragma unroll
      for (int r = 0; r < 4; ++r) {
        const int row = m0 + wr * 32 + mi * 16 + g * 4 + r;
        float v = acc[mi][ni][r] + bb;
        if (ACT) v = gelu_f(v);
        if (OUT_BF16) ((u16*)Cout)[(size_t)row * N + col] = f2bf(v);
        else ((float*)Cout)[(size_t)row * N + col] = v;
      }
    }
  }
}

// ================= decoder layer 1, MFMA: h1d = gelu(gather(kbf)@w1kt^T + h1c + db1) =================
// 64x64 tile, K=64 single-shot; same verified LDS-swizzle/fragment/epilogue layout as mfma64.
// Gather folded into A-stage via idxb row indirection (pre-swizzled source offset, linear LDS write).
__global__ __launch_bounds__(256) void dec1_mfma_kernel(const u16* __restrict__ kbf,
                                                        const int* __restrict__ idxb,
                                                        const float* __restrict__ h1c,
                                                        const u16* __restrict__ w1kt,
                                                        const float* __restrict__ db1,
                                                        u16* __restrict__ h1d) {
  __shared__ u16 As[64 * 64];
  __shared__ u16 Bs[64 * 64];
  const int tid = threadIdx.x;
  const int wave = tid >> 6, lane = tid & 63;
  const int g = lane >> 4, li = lane & 15;
  const int wr = wave >> 1, wc = wave & 1;
  const int r0 = blockIdx.y * 64, c0 = blockIdx.x * 64;
  {
    const int o0 = tid * 16, o1 = o0 + 4096;
    const int ra = o0 >> 7, sa = (o0 >> 4) & 7;
    const int rb = o1 >> 7, sb = (o1 >> 4) & 7;
    const int ia = idxb[r0 + ra], ib = idxb[r0 + rb];
    uint4 va = *(const uint4*)(kbf + (size_t)ia * 64 + ((sa ^ (ra & 7)) << 3));
    uint4 vb = *(const uint4*)(kbf + (size_t)ib * 64 + ((sb ^ (rb & 7)) << 3));
    uint4 wa = *(const uint4*)(w1kt + (size_t)(c0 + ra) * 64 + ((sa ^ (ra & 7)) << 3));
    uint4 wb = *(const uint4*)(w1kt + (size_t)(c0 + rb) * 64 + ((sb ^ (rb & 7)) << 3));
    *(uint4*)((char*)As + o0) = va;
    *(uint4*)((char*)As + o1) = vb;
    *(uint4*)((char*)Bs + o0) = wa;
    *(uint4*)((char*)Bs + o1) = wb;
  }
  __syncthreads();
  f32x4 acc[2][2];
  f32x4 zz = {0.f, 0.f, 0.f, 0.f};
#pragma unroll
  for (int i = 0; i < 2; ++i)
#pragma unroll
    for (int j = 0; j < 2; ++j) acc[i][j] = zz;
#pragma unroll
  for (int ko = 0; ko < 2; ++ko) {
    bf16x8 af[2], bfr[2];
#pragma unroll
    for (int mi = 0; mi < 2; ++mi) {
      const int row = wr * 32 + mi * 16 + li;
      const int sl = (ko * 4 + g) ^ (row & 7);
      af[mi] = *(const bf16x8*)((const char*)As + row * 128 + sl * 16);
    }
#pragma unroll
    for (int ni = 0; ni < 2; ++ni) {
      const int row = wc * 32 + ni * 16 + li;
      const int sl = (ko * 4 + g) ^ (row & 7);
      bfr[ni] = *(const bf16x8*)((const char*)Bs + row * 128 + sl * 16);
    }
#pragma unroll
    for (int mi = 0; mi < 2; ++mi)
#pragma unroll
      for (int ni = 0; ni < 2; ++ni)
        acc[mi][ni] = __builtin_amdgcn_mfma_f32_16x16x32_bf16(af[mi], bfr[ni], acc[mi][ni], 0, 0, 0);
  }
#pragma unroll
  for (int ni = 0; ni < 2; ++ni) {
    const int col = c0 + wc * 32 + ni * 16 + li;
    const float bb = db1[col];
#pragma unroll
    for (int mi = 0; mi < 2; ++mi) {
      const int rowb = r0 + wr * 32 + mi * 16 + g * 4;  // rows rowb..rowb+3 share a query
      const float hv = h1c[(size_t)(rowb >> 3) * 256 + col];
#pragma unroll
      for (int r = 0; r < 4; ++r) {
        float v = acc[mi][ni][r] + hv + bb;
        h1d[(size_t)(rowb + r) * 256 + col] = f2bf(gelu_f(v));
      }
    }
  }
}

// ================= MFMA distance scan: per-(query,chunk) top-4 =================
// grid (256 chunks, 8 q-tiles), block 256 (4 waves, wave = 16 queries)
__global__ __launch_bounds__(256) void dist_scan_kernel(const u16* __restrict__ qbf,
                                                        const float* __restrict__ qn,
                                                        const u16* __restrict__ kbf,
                                                        const float* __restrict__ knorm,
                                                        u64* __restrict__ cand) {
  const int NKEYS = 100000, CK = 391, NCH = 256;
  const int tid = threadIdx.x;
  const int wave = tid >> 6, lane = tid & 63;
  const int g = lane >> 4, qi = lane & 15;
  const int qrow = blockIdx.y * 64 + wave * 16 + qi;
  const bf16x8 b0 = *(const bf16x8*)(qbf + (size_t)qrow * 64 + g * 8);
  const bf16x8 b1 = *(const bf16x8*)(qbf + (size_t)qrow * 64 + 32 + g * 8);
  const float qnv = qn[qrow];
  u64 t[4];
#pragma unroll
  for (int i = 0; i < 4; ++i) t[i] = 0x7F800000FFFFFFFFull;  // d2=+inf, idx=sentinel
  float thr = 3.4e38f;
  const int c0 = blockIdx.x * CK;
  const int c1 = (c0 + CK < NKEYS) ? c0 + CK : NKEYS;
  for (int kt = c0; kt < c1; kt += 16) {
    const u16* kp = kbf + (size_t)(kt + qi) * 64 + g * 8;
    bf16x8 a0 = *(const bf16x8*)(kp);
    bf16x8 a1 = *(const bf16x8*)(kp + 32);
    f32x4 zz = {0.f, 0.f, 0.f, 0.f};
    f32x4 acc = __builtin_amdgcn_mfma_f32_16x16x32_bf16(a0, b0, zz, 0, 0, 0);
    acc = __builtin_amdgcn_mfma_f32_16x16x32_bf16(a1, b1, acc, 0, 0, 0);
    const float4 kn4 = *(const float4*)(knorm + kt + g * 4);
    const float knr[4] = {kn4.x, kn4.y, kn4.z, kn4.w};
    const int kbase = kt + g * 4;
#pragma unroll
    for (int r = 0; r < 4; ++r) {
      const int kidx = kbase + r;
      const float s = fmaf(-2.f, acc[r], knr[r]);
      if (s <= thr && kidx < c1) {  // rare after the first 4 inserts
        float d2 = fmaxf(s + qnv, 0.f);
        u64 c = ((u64)__float_as_uint(d2) << 32) | (unsigned)kidx;
        if (c < t[3]) {
          t[3] = c;
          ce64(t[2], t[3]); ce64(t[1], t[2]); ce64(t[0], t[1]);
        }
        thr = __uint_as_float((unsigned)(t[3] >> 32)) - qnv;
      }
    }
  }
  // merge the 4 lane-groups sharing this query -> chunk top-4
  {
    u64 o[4];
#pragma unroll
    for (int i = 0; i < 4; ++i) o[i] = shflx64(t[i], 16);
    take4(t, o);
#pragma unroll
    for (int i = 0; i < 4; ++i) o[i] = shflx64(t[i], 32);
    take4(t, o);
  }
  if (lane < 16) {
    u64* cp = cand + ((size_t)qrow * NCH + blockIdx.x) * 4;
#pragma unroll
    for (int i = 0; i < 4; ++i) cp[i] = t[i];
  }
}

// ================= merge 256 chunk-top-4 lists -> 4 quarter-top-8s = 32 candidates =================
__global__ __launch_bounds__(256) void merge_kernel(const u64* __restrict__ cand,
                                                    int* __restrict__ cand32) {
  const int q = blockIdx.x * 4 + (threadIdx.x >> 6);
  const int lane = threadIdx.x & 63;
  u64 t[8];
#pragma unroll
  for (int i = 0; i < 8; ++i) t[i] = ~0ull;
  const u64* cp = cand + (size_t)q * 1024 + (size_t)lane * 16;
#pragma unroll
  for (int i = 0; i < 16; ++i) insert8(t, cp[i]);
#pragma unroll
  for (int m = 1; m < 16; m <<= 1) {
    u64 o[8];
#pragma unroll
    for (int i = 0; i < 8; ++i) o[i] = shflx64(t[i], m);
    take8(t, o);
  }
  if ((lane & 15) == 0) {
    int* op = cand32 + q * 32 + (lane >> 4) * 8;
#pragma unroll
    for (int i = 0; i < 8; ++i) op[i] = (int)(unsigned)(t[i] & 0xffffffffull);
  }
}

// ================= exact fp32 re-rank of 32 candidates -> final top-8 =================
__global__ __launch_bounds__(256) void rerank_kernel(const int* __restrict__ cand32,
                                                     const float* __restrict__ qc,
                                                     const float* __restrict__ qn,
                                                     const float* __restrict__ keys,
                                                     const float* __restrict__ knorm,
                                                     int* __restrict__ idxb,
                                                     float* __restrict__ wtsb,
                                                     float* __restrict__ conf) {
  const int sub = threadIdx.x >> 6, lane = threadIdx.x & 63;
  const int q = blockIdx.x * 4 + sub;
  __shared__ float qs[4][64];
  if (lane < 16) *(float4*)(&qs[sub][lane * 4]) = ((const float4*)(qc + (size_t)q * 64))[lane];
  __syncthreads();
  u64 t[8];
#pragma unroll
  for (int i = 0; i < 8; ++i) t[i] = ~0ull;
  if (lane < 32) {
    const int idx = cand32[q * 32 + lane];
    if ((unsigned)idx < 100000u) {
      const float4* kr = (const float4*)(keys + (size_t)idx * 64);
      float a0 = 0.f, a1 = 0.f, a2 = 0.f, a3 = 0.f;
#pragma unroll
      for (int u = 0; u < 16; u += 4) {
        float4 k0 = kr[u], k1 = kr[u + 1], k2 = kr[u + 2], k3 = kr[u + 3];
        float4 q0 = *(const float4*)(&qs[sub][u * 4]), q1 = *(const float4*)(&qs[sub][u * 4 + 4]);
        float4 q2 = *(const float4*)(&qs[sub][u * 4 + 8]), q3 = *(const float4*)(&qs[sub][u * 4 + 12]);
        a0 = fmaf(q0.x, k0.x, a0); a0 = fmaf(q0.y, k0.y, a0); a0 = fmaf(q0.z, k0.z, a0); a0 = fmaf(q0.w, k0.w, a0);
        a1 = fmaf(q1.x, k1.x, a1); a1 = fmaf(q1.y, k1.y, a1); a1 = fmaf(q1.z, k1.z, a1); a1 = fmaf(q1.w, k1.w, a1);
        a2 = fmaf(q2.x, k2.x, a2); a2 = fmaf(q2.y, k2.y, a2); a2 = fmaf(q2.z, k2.z, a2); a2 = fmaf(q2.w, k2.w, a2);
        a3 = fmaf(q3.x, k3.x, a3); a3 = fmaf(q3.y, k3.y, a3); a3 = fmaf(q3.z, k3.z, a3); a3 = fmaf(q3.w, k3.w, a3);
      }
      float dot = (a0 + a1) + (a2 + a3);
      float d2 = fmaf(-2.f, dot, qn[q] + knorm[idx]);
      d2 = fmaxf(d2, 0.f);
      t[0] = ((u64)__float_as_uint(d2) << 32) | (unsigned)idx;
    }
  }
#pragma unroll
  for (int m = 1; m < 64; m <<= 1) {
    u64 o[8];
#pragma unroll
    for (int i = 0; i < 8; ++i) o[i] = shflx64(t[i], m);
    take8(t, o);
  }
  if (lane == 0) {
    float w8[8], s = 0.f;
#pragma unroll
    for (int i = 0; i < 8; ++i) {
      float d = __uint_as_float((unsigned)(t[i] >> 32));
      w8[i] = 1.f / (d + 1e-6f);
      s += w8[i];
    }
    conf[q] = w8[0];
#pragma unroll
    for (int i = 0; i < 8; ++i) {
      idxb[q * 8 + i] = (int)(unsigned)(t[i] & 0xffffffffull);
      wtsb[q * 8 + i] = w8[i] / s;
    }
  }
}

// ================= weighted combine =================
__global__ __launch_bounds__(256) void combine_kernel(const float* __restrict__ dec,
                                                      const float* __restrict__ wtsb,
                                                      float* __restrict__ out) {
  const int b = blockIdx.x, tid = threadIdx.x;
  float w[8];
#pragma unroll
  for (int i = 0; i < 8; ++i) w[i] = wtsb[b * 8 + i];
  const float4* d4 = (const float4*)(dec + (size_t)b * 8192);
  float4 acc = {0.f, 0.f, 0.f, 0.f};
#pragma unroll
  for (int i = 0; i < 8; ++i) {
    float4 v = d4[(size_t)i * 256 + tid];
    acc.x = fmaf(w[i], v.x, acc.x);
    acc.y = fmaf(w[i], v.y, acc.y);
    acc.z = fmaf(w[i], v.z, acc.z);
    acc.w = fmaf(w[i], v.w, acc.w);
  }
  ((float4*)out)[(size_t)b * 256 + tid] = acc;
}

extern "C" void kernel_launch(void* const* d_in, const int* in_sizes, int n_in,
                              void* d_out, int out_size, void* d_ws, size_t ws_size,
                              hipStream_t stream) {
  const float* query   = (const float*)d_in[0];
  const float* context = (const float*)d_in[1];
  const float* keys    = (const float*)d_in[2];
  const float* ew1 = (const float*)d_in[3];
  const float* eb1 = (const float*)d_in[4];
  const float* ew2 = (const float*)d_in[5];
  const float* eb2 = (const float*)d_in[6];
  const float* ew3 = (const float*)d_in[7];
  const float* eb3 = (const float*)d_in[8];
  const float* dw1 = (const float*)d_in[9];
  const float* db1 = (const float*)d_in[10];
  const float* dw2 = (const float*)d_in[11];
  const float* db2 = (const float*)d_in[12];
  const float* dw3 = (const float*)d_in[13];
  const float* db3 = (const float*)d_in[14];
  float* out = (float*)d_out;

  char* ws = (char*)d_ws;
  float* qc     = (float*)(ws + 0);          // 131072
  float* knorm  = (float*)(ws + 131072);     // 100096*4 = 400384
  u16*   qbf    = (u16*)  (ws + 531456);     // 65536
  float* qn     = (float*)(ws + 596992);     // 2048
  float* eh1    = (float*)(ws + 599040);     // 524288
  float* eh2    = (float*)(ws + 1123328);    // 262144
  int*   idxb   = (int*)  (ws + 1385472);    // 16384
  float* wtsb   = (float*)(ws + 1401856);    // 16384
  float* h1c    = (float*)(ws + 1418240);    // 524288
  u16*   kbf    = (u16*)  (ws + 1942528);    // 100096*64*2 = 12812288
  u64*   cand   = (u64*)  (ws + 14754816);   // 512*256*4*8 = 4194304 (dies after merge)
  float* dec    = (float*)(ws + 14754816);   // 4096*1024*4 = 16777216 (aliases cand; written after rerank)
  int*   cand32 = (int*)  (ws + 31532032);   // 512*32*4 = 65536
  u16*   h1d    = (u16*)  (ws + 31597568);   // 4096*256*2 = 2097152
  u16*   h2d    = (u16*)  (ws + 33694720);   // 4096*512*2 = 4194304
  u16*   w2t    = (u16*)  (ws + 37889024);   // 512*256*2 = 262144
  u16*   w3t    = (u16*)  (ws + 38151168);   // 1024*512*2 = 1048576
  u16*   w1ct   = (u16*)  (ws + 39199744);   // 256*1024*2 = 524288
  u16*   cbf    = (u16*)  (ws + 39724032);   // 512*1024*2 = 1048576
  u16*   w1kt   = (u16*)  (ws + 40772608);   // 256*64*2 = 32768    (end 40805376)

  // fused preprocessing: knorm+kbf, w2t, w3t, w1ct, cbf, w1kt
  prep_kernel<<<dim3(1559), dim3(256), 0, stream>>>(keys, knorm, kbf, dw1, w1ct, w1kt,
                                                    dw2, w2t, dw3, w3t, context, cbf);

  // encoder (fp32 exact, bit-identical k-order to prior passing rounds)
  gemm32_kernel<1><<<dim3(8, 16), dim3(256), 0, stream>>>(query, ew1, eb1, eh1, 512, 256, 1024);
  gemm32_kernel<1><<<dim3(4, 16), dim3(256), 0, stream>>>(eh1,   ew2, eb2, eh2, 512, 128, 256);
  gemm32_kernel<0><<<dim3(2, 16), dim3(256), 0, stream>>>(eh2,   ew3, eb3, qc,  512, 64,  128);
  qprep_kernel<<<dim3(2), dim3(256), 0, stream>>>(qc, qbf, qn);

  // shared context part of decoder layer 1 (bf16 MFMA; decode path only)
  mfma64_kernel<0, 0, 0><<<dim3(4, 8), dim3(256), 0, stream>>>(cbf, w1ct, nullptr, h1c,
                                                               512, 256, 1024);

  // selection: MFMA scan (per-chunk top-4) -> merge (32 survivors) -> exact fp32 rerank
  dist_scan_kernel<<<dim3(256, 8), dim3(256), 0, stream>>>(qbf, qn, kbf, knorm, cand);
  merge_kernel<<<dim3(128), dim3(256), 0, stream>>>(cand, cand32);
  rerank_kernel<<<dim3(128), dim3(256), 0, stream>>>(cand32, qc, qn, keys, knorm,
                                                     idxb, wtsb, out + 524288);

  // decoder (dec1 now MFMA with fused gather; no fp32 spill path)
  dec1_mfma_kernel<<<dim3(4, 64), dim3(256), 0, stream>>>(kbf, idxb, h1c, w1kt, db1, h1d);
  mfma64_kernel<1, 1, 1><<<dim3(8, 64),  dim3(256), 0, stream>>>(h1d, w2t, db2, h2d, 4096, 512, 256);
  mfma64_kernel<0, 1, 0><<<dim3(16, 64), dim3(256), 0, stream>>>(h2d, w3t, db3, dec, 4096, 1024, 512);

  // weighted combine
  combine_kernel<<<dim3(512), dim3(256), 0, stream>>>(dec, wtsb, out);
}